// Round 15
// baseline (83.302 us; speedup 1.0000x reference)
//
#include <hip/hip_runtime.h>

// Involution1d fused v8: persistent-block 4-tile pipeline.
// B=16, CH=256, DIM=4096, G=16, K=7, PAD=3, hid=64, K*G=112.
// Grid 256 (1 block/CU), 4 waves; each block runs 4 consecutive (b,l0) tiles
// (TLC=64).  Per tile: regs->xs[buf] -> issue next tile's global loads ->
// lgkm-only barrier (loads stay in flight) -> MFMA kerngen -> ks -> barrier ->
// involution from LDS -> out.  LDS 94.6 KiB, hs/ks separate (2 barriers/tile).
#define BB   16
#define CHN  256
#define DIMN 4096
#define KK   7
#define HID  64
#define KGN  112
#define TLC  64        // columns per tile
#define NT   4         // tiles per block
#define XSD  35        // xs row stride in dw (70 halves: 3 halo + 64 + 3 halo)
#define XSH  70        // xs row stride in halves
#define HSTH 70        // hs row stride in halves
#define KSTD 68        // ks row stride in dw (mult of 4 -> aligned uint4)
#define BN_EPS 1e-5f

typedef __fp16 half2_t __attribute__((ext_vector_type(2)));
typedef __fp16 half8   __attribute__((ext_vector_type(8)));
typedef float  f32x4   __attribute__((ext_vector_type(4)));

union U32H2 { unsigned int u; half2_t h; };

static __device__ __forceinline__ unsigned int packf(float a, float b) {
    U32H2 t; t.h = __builtin_amdgcn_cvt_pkrtz(a, b); return t.u;
}
static __device__ __forceinline__ half2_t ash2(unsigned int u) { U32H2 t; t.u = u; return t.h; }
static __device__ __forceinline__ __fp16 u16h(unsigned short u) {
    return __builtin_bit_cast(__fp16, u);
}
static __device__ __forceinline__ unsigned short hu16(__fp16 h) {
    return __builtin_bit_cast(unsigned short, h);
}

// LDS-only barrier: does NOT drain vmcnt, so global loads issued before it
// stay in flight across the barrier (unlike __syncthreads()).
static __device__ __forceinline__ void bar_lds() {
    asm volatile("s_waitcnt lgkmcnt(0)" ::: "memory");
    __builtin_amdgcn_s_barrier();
    __builtin_amdgcn_sched_barrier(0);
}

// ---------------------------------------------------------------------------
__global__ __launch_bounds__(256) void setup_k(
    const float* __restrict__ w1, const float* __restrict__ w2,
    const float* __restrict__ bn_gamma, const float* __restrict__ bn_beta,
    const float* __restrict__ bn_mean,  const float* __restrict__ bn_var,
    __fp16* __restrict__ w1f, __fp16* __restrict__ w2f,
    float* __restrict__ scb, float* __restrict__ shb) {
    int t = blockIdx.x * 256 + threadIdx.x;   // grid covers 16384
    if (t < HID * CHN) w1f[t] = (__fp16)w1[t];
    if (t < KGN * HID) w2f[t] = (__fp16)w2[t];
    if (t < HID) {
        float s = bn_gamma[t] * rsqrtf(bn_var[t] + BN_EPS);
        scb[t] = s;
        shb[t] = bn_beta[t] - bn_mean[t] * s;
    }
}

// ---------------------------------------------------------------------------
template <int OFF>
static __device__ __forceinline__ void extract_kv(const uint4 q[4], float kv[KK][4]) {
#pragma unroll
    for (int k = 0; k < KK; ++k) {
        const int kk = k + OFF;
        const int i  = kk >> 1;
        const int h  = kk & 1;
#pragma unroll
        for (int j = 0; j < 4; ++j) {
            unsigned int u = (&q[i].x)[j];
            half2_t hh = ash2(u);
            kv[k][j] = h ? (float)hh[1] : (float)hh[0];
        }
    }
}

// ---------------------------------------------------------------------------
static __device__ __forceinline__ void load_tile(
    const float* __restrict__ x, int b, int l0, int colq, int chl, int trow,
    float4 v[16], float4& lv, float4& rv) {
    const float* xg = x + ((size_t)b * CHN + chl) * DIMN + l0 + 4 * colq;
#pragma unroll
    for (int i = 0; i < 16; ++i)
        v[i] = *(const float4*)(xg + (size_t)(16 * i) * DIMN);
    const float* xrow = x + ((size_t)b * CHN + trow) * DIMN;
    lv = (l0 > 0) ? *(const float4*)(xrow + l0 - 4)
                  : make_float4(0.f, 0.f, 0.f, 0.f);
    rv = (l0 + TLC < DIMN) ? *(const float4*)(xrow + l0 + TLC)
                           : make_float4(0.f, 0.f, 0.f, 0.f);
}

static __device__ __forceinline__ void store_tile(
    unsigned int* xs, int colq, int chl, int trow,
    const float4 v[16], const float4 lv, const float4 rv) {
    unsigned short* xs16 = (unsigned short*)xs;
#pragma unroll
    for (int i = 0; i < 16; ++i) {
        unsigned short* rp = xs16 + (chl + 16 * i) * XSH + 4 * colq + 3;
        rp[0] = hu16((__fp16)v[i].x);
        *(unsigned int*)(rp + 1) = packf(v[i].y, v[i].z);
        rp[3] = hu16((__fp16)v[i].w);
    }
    unsigned short* hp = xs16 + trow * XSH;
    hp[0]  = hu16((__fp16)lv.y);
    hp[1]  = hu16((__fp16)lv.z);
    hp[2]  = hu16((__fp16)lv.w);
    hp[67] = hu16((__fp16)rv.x);
    hp[68] = hu16((__fp16)rv.y);
    hp[69] = hu16((__fp16)rv.z);
}

// ---------------------------------------------------------------------------
// Fragment maps (16x16x32): A[m][k]: m=lane&15, k=8*((lane>>4)&3)+j;
// B[k][n]: n=lane&15; D[m][n]: n=lane&15, m=4*((lane>>4)&3)+reg.
__global__ __launch_bounds__(256, 1) void fused_k(
    const float* __restrict__ x,
    const __fp16* __restrict__ w1f,
    const float* __restrict__ b1,
    const float* __restrict__ scb, const float* __restrict__ shb,
    const __fp16* __restrict__ w2f,
    const float* __restrict__ b2,
    float* __restrict__ out) {
    __shared__ unsigned int   xs0[CHN * XSD];   // 35840 B
    __shared__ unsigned int   xs1[CHN * XSD];   // 35840 B
    __shared__ unsigned short hsb[HID * HSTH];  // 8960 B
    __shared__ unsigned int   ksb[56 * KSTD];   // 15232 B   (total 94.6 KiB)

    const int t    = threadIdx.x;          // 0..255
    const int lane = t & 63;
    const int w    = t >> 6;               // wave 0..3
    const int lr   = t & 15;
    const int lg   = (t >> 4) & 3;
    const int colL = 16 * w + lr;          // wave's column (0..63)
    const int colq = t & 15;               // staging col quad
    const int chl  = t >> 4;               // staging row base

    float4 v[16], lv, rv;

    // prologue: load tile 0
    {
        const int tid0 = blockIdx.x * NT;
        load_tile(x, tid0 >> 6, (tid0 & 63) * TLC, colq, chl, t, v, lv, rv);
    }

#pragma unroll 2
    for (int tt = 0; tt < NT; ++tt) {
        const int ctid = blockIdx.x * NT + tt;
        const int b    = ctid >> 6;
        const int l0   = (ctid & 63) * TLC;
        unsigned int*   xs   = (tt & 1) ? xs1 : xs0;
        unsigned short* xs16 = (unsigned short*)xs;

        // ---- write current tile regs -> xs[buf]
        store_tile(xs, colq, chl, t, v, lv, rv);

        // ---- issue next tile's global loads (stay in flight across barrier)
        if (tt + 1 < NT) {
            const int ntid = ctid + 1;
            load_tile(x, ntid >> 6, (ntid & 63) * TLC, colq, chl, t, v, lv, rv);
        }
        bar_lds();

        // ---- Phase 1: h = w1 . x  (4 o-frags x 8 K-steps) ----
        f32x4 acc[4];
#pragma unroll
        for (int of = 0; of < 4; ++of) acc[of] = (f32x4){0.f, 0.f, 0.f, 0.f};

#pragma unroll
        for (int p = 0; p < 8; ++p) {
            half8 bf;
#pragma unroll
            for (int j = 0; j < 8; ++j)
                bf[j] = u16h(xs16[(32 * p + 8 * lg + j) * XSH + colL + 3]);
#pragma unroll
            for (int of = 0; of < 4; ++of) {
                half8 af = *(const half8*)(w1f + (16 * of + lr) * CHN + 32 * p + 8 * lg);
                acc[of] = __builtin_amdgcn_mfma_f32_16x16x32_f16(af, bf, acc[of], 0, 0, 0);
            }
        }

        // ---- bias + relu + BN; h -> hsb (wave-private cols)
#pragma unroll
        for (int of = 0; of < 4; ++of) {
#pragma unroll
            for (int r = 0; r < 4; ++r) {
                const int o = 16 * of + 4 * lg + r;
                float hv = fmaxf(acc[of][r] + b1[o], 0.f) * scb[o] + shb[o];
                hsb[o * HSTH + colL] = hu16((__fp16)hv);
            }
        }

        // ---- Phase 2: kern = w2 . h  (7 r-frags x 2 K-steps) ----
        f32x4 acc2[7];
#pragma unroll
        for (int rf = 0; rf < 7; ++rf) acc2[rf] = (f32x4){0.f, 0.f, 0.f, 0.f};

#pragma unroll
        for (int kx = 0; kx < 2; ++kx) {
            half8 bf;
#pragma unroll
            for (int j = 0; j < 8; ++j)
                bf[j] = u16h(hsb[(32 * kx + 8 * lg + j) * HSTH + colL]);
#pragma unroll
            for (int rf = 0; rf < 7; ++rf) {
                half8 af = *(const half8*)(w2f + (16 * rf + lr) * HID + 32 * kx + 8 * lg);
                acc2[rf] = __builtin_amdgcn_mfma_f32_16x16x32_f16(af, bf, acc2[rf], 0, 0, 0);
            }
        }

        // ---- bias + row-pair pack -> ksb
#pragma unroll
        for (int rf = 0; rf < 7; ++rf) {
#pragma unroll
            for (int p2 = 0; p2 < 2; ++p2) {
                const int r0 = 16 * rf + 4 * lg + 2 * p2;
                float k0 = acc2[rf][2 * p2 + 0] + b2[r0 + 0];
                float k1 = acc2[rf][2 * p2 + 1] + b2[r0 + 1];
                ksb[(r0 >> 1) * KSTD + colL] = packf(k0, k1);
            }
        }
        bar_lds();

        // ---- Involution: wave w -> groups {4w..4w+3}; taps from LDS f16 ----
        const int q4    = lane & 15;
        const int hi    = lane >> 4;           // 0..3
        const int cbase = 4 * q4;

#pragma unroll
        for (int gi = 0; gi < 4; ++gi) {
            const int g   = 4 * w + gi;        // parity = gi & 1 (4w even)
            const int rpb = (7 * g) >> 1;
            uint4 qq[4];
#pragma unroll
            for (int ii = 0; ii < 4; ++ii)
                qq[ii] = *(const uint4*)(ksb + (rpb + ii) * KSTD + cbase);
            float kv[KK][4];
            if ((gi & 1) == 0) extract_kv<0>(qq, kv);
            else               extract_kv<1>(qq, kv);

#pragma unroll
            for (int i2 = 0; i2 < 4; ++i2) {
                const int ch = 16 * g + 4 * i2 + hi;
                const unsigned int* xr = xs + ch * XSD + (cbase >> 1);
                unsigned int uu[5];
#pragma unroll
                for (int j = 0; j < 5; ++j) uu[j] = xr[j];
                float xv[10];
#pragma unroll
                for (int r = 0; r < 10; ++r) {
                    half2_t hh = ash2(uu[r >> 1]);
                    xv[r] = (r & 1) ? (float)hh[1] : (float)hh[0];
                }
                float o0 = 0.f, o1 = 0.f, o2 = 0.f, o3 = 0.f;
#pragma unroll
                for (int k = 0; k < KK; ++k) {
                    o0 = fmaf(kv[k][0], xv[k + 0], o0);
                    o1 = fmaf(kv[k][1], xv[k + 1], o1);
                    o2 = fmaf(kv[k][2], xv[k + 2], o2);
                    o3 = fmaf(kv[k][3], xv[k + 3], o3);
                }
                *(float4*)(out + ((size_t)b * CHN + ch) * DIMN + l0 + cbase) =
                    make_float4(o0, o1, o2, o3);
            }
        }
        // next iteration writes the other xs buffer; hs/ks writes are fenced
        // by that iteration's bar_lds() after its store_tile.
    }
}

// ---------------------------------------------------------------------------
extern "C" void kernel_launch(void* const* d_in, const int* in_sizes, int n_in,
                              void* d_out, int out_size, void* d_ws, size_t ws_size,
                              hipStream_t stream) {
    (void)in_sizes; (void)n_in; (void)out_size; (void)ws_size;

    const float* x        = (const float*)d_in[0];
    const float* w1       = (const float*)d_in[1];
    const float* b1       = (const float*)d_in[2];
    const float* bn_gamma = (const float*)d_in[3];
    const float* bn_beta  = (const float*)d_in[4];
    const float* bn_mean  = (const float*)d_in[5];
    const float* bn_var   = (const float*)d_in[6];
    const float* w2       = (const float*)d_in[7];
    const float* b2       = (const float*)d_in[8];
    float*       out      = (float*)d_out;

    __fp16* w1f = (__fp16*)d_ws;                 // 16384 f16
    __fp16* w2f = w1f + HID * CHN;               // 7168 f16
    float*  scb = (float*)(w2f + KGN * HID);     // 64
    float*  shb = scb + HID;                     // 64

    setup_k<<<(HID * CHN + 255) / 256, 256, 0, stream>>>(
        w1, w2, bn_gamma, bn_beta, bn_mean, bn_var, w1f, w2f, scb, shb);
    fused_k<<<(BB * (DIMN / TLC)) / NT, 256, 0, stream>>>(
        x, w1f, b1, scb, shb, w2f, b2, out);
}